// Round 1
// baseline (418.697 us; speedup 1.0000x reference)
//
#include <hip/hip_runtime.h>

// Mamba-2 SSD chunked scan.
// b=4, s=8192, h=32, p=64, n=16, block_len=64, chunks=128.
#define BB 4
#define SS 8192
#define HH 32
#define PP 64
#define NN 16
#define LL 64
#define CC 128

// ---------------------------------------------------------------------------
// K1: per (b,c,h) chunk -> per-chunk end states  S[p][n] and A_last.
// S[p][n] = sum_l X[l][p] * exp(cs[63]-cs[l]) * B[l][n]
// ---------------------------------------------------------------------------
__global__ __launch_bounds__(256) void k1_states(
    const float* __restrict__ X, const float* __restrict__ A,
    const float* __restrict__ B, float* __restrict__ states,
    float* __restrict__ a_last)
{
    int blk = blockIdx.x;
    int h = blk & (HH - 1);
    int c = (blk / HH) & (CC - 1);
    int b = blk / (HH * CC);
    int tid = threadIdx.x;

    __shared__ float Xs[LL][PP];   // 16 KB, becomes X*decay
    __shared__ float Bs[LL][NN];   // 4 KB
    __shared__ float cs[LL];

    const size_t row0 = (size_t)b * SS + (size_t)c * LL;
    const float* Xp = X + (row0 * HH + h) * PP;
    const float* Bp = B + (row0 * HH + h) * NN;
    const float* Ap = A + row0 * HH + h;

    // load X chunk (64x64), coalesced: 4 rows per 256-thread read
#pragma unroll
    for (int k = 0; k < 16; ++k) {
        int e = tid + k * 256;
        Xs[e >> 6][e & 63] = Xp[(size_t)(e >> 6) * (HH * PP) + (e & 63)];
    }
    // load B chunk (64x16)
#pragma unroll
    for (int k = 0; k < 4; ++k) {
        int e = tid + k * 256;
        Bs[e >> 4][e & 15] = Bp[(size_t)(e >> 4) * (HH * NN) + (e & 15)];
    }
    if (tid < LL) cs[tid] = Ap[(size_t)tid * HH];
    __syncthreads();
    if (tid == 0) {
        float acc = 0.f;
        for (int i = 0; i < LL; ++i) { acc += cs[i]; cs[i] = acc; }
    }
    __syncthreads();
    float alast = cs[LL - 1];
    // scale own X elements by decay (same indices this thread wrote)
#pragma unroll
    for (int k = 0; k < 16; ++k) {
        int e = tid + k * 256;
        int r = e >> 6;
        Xs[r][e & 63] *= __expf(alast - cs[r]);
    }
    __syncthreads();

    // states[p][nb..nb+3] per thread; offset = tid*4 -> fully coalesced write
    int p  = tid >> 2;
    int nb = (tid & 3) << 2;
    float4 acc = {0.f, 0.f, 0.f, 0.f};
    for (int l = 0; l < LL; ++l) {
        float xv = Xs[l][p];
        const float4 bv = *(const float4*)&Bs[l][nb];
        acc.x += xv * bv.x; acc.y += xv * bv.y;
        acc.z += xv * bv.z; acc.w += xv * bv.w;
    }
    size_t bh = (size_t)b * HH + h;
    float* sp = states + ((bh * CC + c) * PP + p) * NN + nb;
    *(float4*)sp = acc;
    if (tid == 0) a_last[bh * CC + c] = alast;
}

// ---------------------------------------------------------------------------
// K2: inter-chunk scan, in place.  P[0]=0; P[c]=exp(al[c-1])*P[c-1]+S[c-1].
// One thread per (b,h,p,n); consecutive threads -> consecutive (p,n): coalesced.
// ---------------------------------------------------------------------------
__global__ __launch_bounds__(256) void k2_scan(
    float* __restrict__ states, const float* __restrict__ a_last)
{
    int idx = blockIdx.x * 256 + threadIdx.x;
    int pn = idx & (PP * NN - 1);
    int bh = idx >> 10;                 // PP*NN = 1024
    float* base = states + (size_t)bh * CC * (PP * NN) + pn;
    const float* al = a_last + (size_t)bh * CC;
    float carry = 0.f;
    for (int c = 0; c < CC; ++c) {
        float s = base[(size_t)c * (PP * NN)];
        base[(size_t)c * (PP * NN)] = carry;       // P[c]
        carry = __expf(al[c]) * carry + s;          // P[c+1]
    }
}

// ---------------------------------------------------------------------------
// K3: per (b,c,h) chunk -> Y = Y_diag + Y_off.
// Sc[i][j] = (C[i]·B[j]) * exp(cs[i]-cs[j])   (j<=i, else 0), stored transposed.
// Y[i][p] = sum_j Sc[i][j]*X[j][p] + exp(cs[i]) * sum_n C[i][n]*P[p][n]
// ---------------------------------------------------------------------------
__global__ __launch_bounds__(256) void k3_y(
    const float* __restrict__ X, const float* __restrict__ A,
    const float* __restrict__ Bm, const float* __restrict__ Cm,
    const float* __restrict__ Pst, float* __restrict__ Y)
{
    int blk = blockIdx.x;
    int h = blk & (HH - 1);
    int c = (blk / HH) & (CC - 1);
    int b = blk / (HH * CC);
    int tid = threadIdx.x;

    __shared__ float Xs[LL][PP];     // 16 KB
    __shared__ float ScT[LL][68];    // transposed scores, +4 pad keeps 16B align
    __shared__ float Bs[LL][NN];     // 4 KB
    __shared__ float Cs[LL][17];     // +1 pad: scalar reads, break stride-16
    __shared__ float Ps[PP][17];     // +1 pad
    __shared__ float cs[LL];

    const size_t row0 = (size_t)b * SS + (size_t)c * LL;
    const float* Xp = X + (row0 * HH + h) * PP;
    const float* Bp = Bm + (row0 * HH + h) * NN;
    const float* Cp = Cm + (row0 * HH + h) * NN;
    const float* Ap = A + row0 * HH + h;
    size_t bh = (size_t)b * HH + h;
    const float* Pp = Pst + (bh * CC + c) * (PP * NN);

#pragma unroll
    for (int k = 0; k < 16; ++k) {
        int e = tid + k * 256;
        Xs[e >> 6][e & 63] = Xp[(size_t)(e >> 6) * (HH * PP) + (e & 63)];
    }
#pragma unroll
    for (int k = 0; k < 4; ++k) {
        int e = tid + k * 256;
        int r = e >> 4, col = e & 15;
        Bs[r][col] = Bp[(size_t)r * (HH * NN) + col];
        Cs[r][col] = Cp[(size_t)r * (HH * NN) + col];
        Ps[r][col] = Pp[e];
    }
    if (tid < LL) cs[tid] = Ap[(size_t)tid * HH];
    __syncthreads();
    if (tid == 0) {
        float acc = 0.f;
        for (int i = 0; i < LL; ++i) { acc += cs[i]; cs[i] = acc; }
    }
    __syncthreads();

    // scores, written transposed: per k, j fixed per 64-lane group, i = tid&63
#pragma unroll
    for (int k = 0; k < 16; ++k) {
        int e = tid + k * 256;
        int j = e >> 6;
        int i = e & 63;
        float d = 0.f;
#pragma unroll
        for (int n = 0; n < NN; ++n) d += Cs[i][n] * Bs[j][n];
        ScT[j][i] = (j <= i) ? d * __expf(cs[i] - cs[j]) : 0.f;
    }
    __syncthreads();

    // 4x4 register tile: i = i0+di, p = p0+dp
    int i0 = (tid >> 4) << 2;
    int p0 = (tid & 15) << 2;
    float acc[4][4] = {};
    for (int j = 0; j < LL; ++j) {
        const float4 sc = *(const float4*)&ScT[j][i0];
        const float4 xv = *(const float4*)&Xs[j][p0];
        const float s[4] = {sc.x, sc.y, sc.z, sc.w};
        const float x[4] = {xv.x, xv.y, xv.z, xv.w};
#pragma unroll
        for (int a = 0; a < 4; ++a)
#pragma unroll
            for (int q = 0; q < 4; ++q)
                acc[a][q] += s[a] * x[q];
    }

    float* Yp = Y + (row0 * HH + h) * PP;
#pragma unroll
    for (int di = 0; di < 4; ++di) {
        int i = i0 + di;
        float ei = __expf(cs[i]);
        float rr[4];
#pragma unroll
        for (int dp = 0; dp < 4; ++dp) {
            float d = 0.f;
#pragma unroll
            for (int n = 0; n < NN; ++n) d += Cs[i][n] * Ps[p0 + dp][n];
            rr[dp] = acc[di][dp] + ei * d;
        }
        float4 r = {rr[0], rr[1], rr[2], rr[3]};
        *(float4*)(Yp + (size_t)i * (HH * PP) + p0) = r;
    }
}

// ---------------------------------------------------------------------------
extern "C" void kernel_launch(void* const* d_in, const int* in_sizes, int n_in,
                              void* d_out, int out_size, void* d_ws, size_t ws_size,
                              hipStream_t stream)
{
    const float* X = (const float*)d_in[0];
    const float* A = (const float*)d_in[1];
    const float* B = (const float*)d_in[2];
    const float* C = (const float*)d_in[3];
    float* Y = (float*)d_out;

    float* states = (float*)d_ws;                                  // 64 MiB
    float* a_last = states + (size_t)BB * HH * CC * PP * NN;       // 64 KiB

    dim3 blk(256);
    k1_states<<<dim3(BB * CC * HH), blk, 0, stream>>>(X, A, B, states, a_last);
    k2_scan<<<dim3((BB * HH * PP * NN) / 256), blk, 0, stream>>>(states, a_last);
    k3_y<<<dim3(BB * CC * HH), blk, 0, stream>>>(X, A, B, C, states, Y);
}

// Round 2
// 263.009 us; speedup vs baseline: 1.5919x; 1.5919x over previous
//
#include <hip/hip_runtime.h>

// Mamba-2 SSD chunked scan. b=4, s=8192, h=32, p=64, n=16, l=64, c=128.
#define BB 4
#define SS 8192
#define HH 32
#define PP 64
#define NN 16
#define LL 64
#define CC 128

typedef __attribute__((ext_vector_type(8))) short bf16x8;
typedef __attribute__((ext_vector_type(4))) short bf16x4;
typedef __attribute__((ext_vector_type(4))) float f32x4;

__device__ inline short f2bf(float f) {
    unsigned u = __builtin_bit_cast(unsigned, f);
    u = (u + 0x7FFFu + ((u >> 16) & 1u)) >> 16;
    return (short)u;
}

// ---------------------------------------------------------------------------
// K1: per (b,c,h) chunk -> per-chunk end states S[p][n] and A_last.
// ---------------------------------------------------------------------------
__global__ __launch_bounds__(256) void k1_states(
    const float* __restrict__ X, const float* __restrict__ A,
    const float* __restrict__ B, float* __restrict__ states,
    float* __restrict__ a_last)
{
    int blk = blockIdx.x;
    int h = blk & (HH - 1);
    int c = (blk / HH) & (CC - 1);
    int b = blk / (HH * CC);
    int tid = threadIdx.x;

    __shared__ float Xs[LL][PP];
    __shared__ float Bs[LL][NN];
    __shared__ float cs[LL];

    const size_t row0 = (size_t)b * SS + (size_t)c * LL;
    const float* Xp = X + (row0 * HH + h) * PP;
    const float* Bp = B + (row0 * HH + h) * NN;
    const float* Ap = A + row0 * HH + h;

#pragma unroll
    for (int k = 0; k < 16; ++k) {
        int e = tid + k * 256;
        Xs[e >> 6][e & 63] = Xp[(size_t)(e >> 6) * (HH * PP) + (e & 63)];
    }
#pragma unroll
    for (int k = 0; k < 4; ++k) {
        int e = tid + k * 256;
        Bs[e >> 4][e & 15] = Bp[(size_t)(e >> 4) * (HH * NN) + (e & 15)];
    }
    // wave-parallel inclusive scan of A (wave 0)
    if (tid < 64) {
        float x = Ap[(size_t)tid * HH];
#pragma unroll
        for (int d = 1; d < 64; d <<= 1) {
            float t = __shfl_up(x, d, 64);
            if (tid >= d) x += t;
        }
        cs[tid] = x;
    }
    __syncthreads();
    float alast = cs[LL - 1];
#pragma unroll
    for (int k = 0; k < 16; ++k) {
        int e = tid + k * 256;
        int r = e >> 6;
        Xs[r][e & 63] *= __expf(alast - cs[r]);
    }
    __syncthreads();

    int p  = tid >> 2;
    int nb = (tid & 3) << 2;
    float4 acc = {0.f, 0.f, 0.f, 0.f};
    for (int l = 0; l < LL; ++l) {
        float xv = Xs[l][p];
        const float4 bv = *(const float4*)&Bs[l][nb];
        acc.x += xv * bv.x; acc.y += xv * bv.y;
        acc.z += xv * bv.z; acc.w += xv * bv.w;
    }
    size_t bh = (size_t)b * HH + h;
    float* sp = states + ((bh * CC + c) * PP + p) * NN + nb;
    *(float4*)sp = acc;
    if (tid == 0) a_last[bh * CC + c] = alast;
}

// ---------------------------------------------------------------------------
// K2: inter-chunk scan, in place, unrolled x8 to batch memory latency.
// ---------------------------------------------------------------------------
__global__ __launch_bounds__(256) void k2_scan(
    float* __restrict__ states, const float* __restrict__ a_last)
{
    int idx = blockIdx.x * 256 + threadIdx.x;
    int pn = idx & (PP * NN - 1);
    int bh = idx >> 10;
    float* base = states + (size_t)bh * CC * (PP * NN) + pn;
    const float* al = a_last + (size_t)bh * CC;
    float carry = 0.f;
    for (int c0 = 0; c0 < CC; c0 += 8) {
        float s[8], av[8], o[8];
#pragma unroll
        for (int u = 0; u < 8; ++u) s[u] = base[(size_t)(c0 + u) * (PP * NN)];
#pragma unroll
        for (int u = 0; u < 8; ++u) av[u] = al[c0 + u];
#pragma unroll
        for (int u = 0; u < 8; ++u) { o[u] = carry; carry = __expf(av[u]) * carry + s[u]; }
#pragma unroll
        for (int u = 0; u < 8; ++u) base[(size_t)(c0 + u) * (PP * NN)] = o[u];
    }
}

// ---------------------------------------------------------------------------
// K3: per (b,c,h) chunk -> Y via MFMA (bf16 inputs, f32 accumulate).
// All MFMA operands in fragment-contiguous LDS (slot*16B per lane).
// Wave w owns output row-strip i in [16w, 16w+16).
// ---------------------------------------------------------------------------
__global__ __launch_bounds__(256) void k3_y(
    const float* __restrict__ X, const float* __restrict__ A,
    const float* __restrict__ Bm, const float* __restrict__ Cm,
    const float* __restrict__ Pst, float* __restrict__ Y)
{
    int blk = blockIdx.x;
    int h = blk & (HH - 1);
    int c = (blk / HH) & (CC - 1);
    int b = blk / (HH * CC);
    int tid = threadIdx.x;
    int w = tid >> 6, l = tid & 63, g = l >> 4, lr = l & 15;

    __shared__ short ScF[8 * 64 * 8];  // A-frags of scores: slot (w*2+kt)*64+lane
    __shared__ short XTF[8 * 64 * 8];  // B-frags of X:      slot (kt*4+pt)*64+lane
    __shared__ short CsF[4 * 64 * 8];  // A-frags of C:      slot it*64+lane (K padded 16->32)
    __shared__ short BsF[4 * 64 * 8];  // B-frags of B:      slot jt*64+lane
    __shared__ short PsF[4 * 64 * 8];  // B-frags of P:      slot pt*64+lane
    __shared__ float csL[64];

    const size_t row0 = (size_t)b * SS + (size_t)c * LL;
    const float* Xp = X + (row0 * HH + h) * PP;
    const float* Bp = Bm + (row0 * HH + h) * NN;
    const float* Cp = Cm + (row0 * HH + h) * NN;
    const float* Ap = A + row0 * HH + h;
    size_t bh = (size_t)b * HH + h;
    const float* Pp = Pst + (bh * CC + c) * (PP * NN);
    float* Yp = Y + (row0 * HH + h) * PP;

    // zero score-frag region (covers never-written upper-triangular tiles)
    ((bf16x8*)ScF)[tid] = (bf16x8)0;
    ((bf16x8*)ScF)[tid + 256] = (bf16x8)0;

    // A cumsum: wave-parallel scan on wave 0
    if (tid < 64) {
        float x = Ap[(size_t)tid * HH];
#pragma unroll
        for (int d = 1; d < 64; d <<= 1) {
            float t = __shfl_up(x, d, 64);
            if (tid >= d) x += t;
        }
        csL[tid] = x;
    }

    // stage B, C, P as bf16 fragments (K-halves >=16 zeroed)
    {
        int r = tid >> 2, q = tid & 3;
        int fl = (r & 15) + 16 * (q >> 1);
        int jt = r >> 4;
        float4 bv = *(const float4*)(Bp + (size_t)r * (HH * NN) + q * 4);
        float4 cv = *(const float4*)(Cp + (size_t)r * (HH * NN) + q * 4);
        float4 pv = *(const float4*)(Pp + tid * 4);
        bf16x4 bb = { f2bf(bv.x), f2bf(bv.y), f2bf(bv.z), f2bf(bv.w) };
        bf16x4 cc = { f2bf(cv.x), f2bf(cv.y), f2bf(cv.z), f2bf(cv.w) };
        bf16x4 pp = { f2bf(pv.x), f2bf(pv.y), f2bf(pv.z), f2bf(pv.w) };
        ((bf16x4*)BsF)[(jt * 64 + fl) * 2 + (q & 1)] = bb;
        ((bf16x4*)CsF)[(jt * 64 + fl) * 2 + (q & 1)] = cc;
        ((bf16x4*)PsF)[(jt * 64 + fl) * 2 + (q & 1)] = pp;
        int zt = tid >> 6, zu = (tid >> 1) & 31, zv = tid & 1;
        bf16x4 z = (bf16x4)0;
        ((bf16x4*)BsF)[(zt * 64 + 32 + zu) * 2 + zv] = z;
        ((bf16x4*)CsF)[(zt * 64 + 32 + zu) * 2 + zv] = z;
        ((bf16x4*)PsF)[(zt * 64 + 32 + zu) * 2 + zv] = z;
    }

    // stage X transposed into B-fragments (scattered dword loads)
#pragma unroll
    for (int si = 0; si < 2; ++si) {
        int s = tid + si * 256;
        int sl = s & 63, pt = (s >> 6) & 3, kt = s >> 8;
        int p = pt * 16 + (sl & 15);
        int k0 = kt * 32 + (sl >> 4) * 8;
        float xv[8];
#pragma unroll
        for (int e = 0; e < 8; ++e)
            xv[e] = Xp[(size_t)(k0 + e) * (HH * PP) + p];
        bf16x8 xb;
#pragma unroll
        for (int e = 0; e < 8; ++e) xb[e] = f2bf(xv[e]);
        ((bf16x8*)XTF)[s] = xb;
    }

    __syncthreads();

    // hoisted cs values for this lane's 4 output rows
    float cs_i[4];
    int ib = w * 16 + g * 4;
#pragma unroll
    for (int r = 0; r < 4; ++r) cs_i[r] = csL[ib + r];

    bf16x8 caw = ((bf16x8*)CsF)[w * 64 + l];

    // --- scores: Sc[i][j] = (C[i]·B[j]) * exp(cs_i - cs_j), j<=i ---
    for (int jt = 0; jt <= w; ++jt) {
        bf16x8 bw = ((bf16x8*)BsF)[jt * 64 + l];
        f32x4 sr = __builtin_amdgcn_mfma_f32_16x16x32_bf16(caw, bw, (f32x4)0.f, 0, 0, 0);
        int j = jt * 16 + lr;
        float csj = csL[j];
        int kt = j >> 5;
        int flb = 16 * ((j >> 3) & 3);
#pragma unroll
        for (int r = 0; r < 4; ++r) {
            int i15 = g * 4 + r;
            int i = w * 16 + i15;
            float v = (j <= i) ? sr[r] * __expf(cs_i[r] - csj) : 0.f;
            ScF[((w * 2 + kt) * 64 + i15 + flb) * 8 + (j & 7)] = f2bf(v);
        }
    }

    // --- Y_off: acc = (C·P^T), then scale rows by exp(cs_i) ---
    f32x4 acc[4];
#pragma unroll
    for (int pt = 0; pt < 4; ++pt) {
        bf16x8 pw = ((bf16x8*)PsF)[pt * 64 + l];
        acc[pt] = __builtin_amdgcn_mfma_f32_16x16x32_bf16(caw, pw, (f32x4)0.f, 0, 0, 0);
    }
    float ei[4];
#pragma unroll
    for (int r = 0; r < 4; ++r) ei[r] = __expf(cs_i[r]);
#pragma unroll
    for (int pt = 0; pt < 4; ++pt)
#pragma unroll
        for (int r = 0; r < 4; ++r) acc[pt][r] *= ei[r];

    // --- main: acc += Sc · X  (K = 64, wave w needs kt where 32kt <= 16w+15) ---
    int kts = (w >= 2) ? 2 : 1;
    for (int kt = 0; kt < kts; ++kt) {
        bf16x8 af = ((bf16x8*)ScF)[(w * 2 + kt) * 64 + l];
#pragma unroll
        for (int pt = 0; pt < 4; ++pt) {
            bf16x8 xf = ((bf16x8*)XTF)[(kt * 4 + pt) * 64 + l];
            acc[pt] = __builtin_amdgcn_mfma_f32_16x16x32_bf16(af, xf, acc[pt], 0, 0, 0);
        }
    }

    // --- store Y (f32): i = 16w + 4g + r, p = 16pt + lr ---
#pragma unroll
    for (int pt = 0; pt < 4; ++pt)
#pragma unroll
        for (int r = 0; r < 4; ++r) {
            int i = w * 16 + g * 4 + r;
            Yp[(size_t)i * (HH * PP) + pt * 16 + lr] = acc[pt][r];
        }
}

// ---------------------------------------------------------------------------
extern "C" void kernel_launch(void* const* d_in, const int* in_sizes, int n_in,
                              void* d_out, int out_size, void* d_ws, size_t ws_size,
                              hipStream_t stream)
{
    const float* X = (const float*)d_in[0];
    const float* A = (const float*)d_in[1];
    const float* B = (const float*)d_in[2];
    const float* C = (const float*)d_in[3];
    float* Y = (float*)d_out;

    float* states = (float*)d_ws;
    float* a_last = states + (size_t)BB * HH * CC * PP * NN;

    dim3 blk(256);
    k1_states<<<dim3(BB * CC * HH), blk, 0, stream>>>(X, A, B, states, a_last);
    k2_scan<<<dim3((BB * HH * PP * NN) / 256), blk, 0, stream>>>(states, a_last);
    k3_y<<<dim3(BB * CC * HH), blk, 0, stream>>>(X, A, B, C, states, Y);
}